// Round 1
// baseline (152.947 us; speedup 1.0000x reference)
//
#include <hip/hip_runtime.h>
#include <hip/hip_bf16.h>
#include <cstdint>

typedef __bf16 bf16x8 __attribute__((ext_vector_type(8)));
typedef float  f32x4  __attribute__((ext_vector_type(4)));

#define B_ 4
#define S_ 2048
#define D_ 256
#define H_ 8
#define E_ 32

// scale = d_model^-0.5 folded into Q, plus log2(e) so softmax uses exp2 directly
#define QSCALE (0.0625f * 1.44269504088896f)

__device__ inline unsigned short bfbits(float f) {
    return __builtin_bit_cast(unsigned short, (__bf16)f);
}
__device__ inline unsigned int pack2(float a, float b) {
    return (unsigned int)bfbits(a) | ((unsigned int)bfbits(b) << 16);
}

// ---------------------------------------------------------------------------
// Kernel A: QKV projection.  grid (24, 128), block 256.
//   blockIdx.x = ho: op = ho>>3 (0=Q,1=K,2=V), h = ho&7
//   blockIdx.y = rt: 64-row tile of the 8192 x-rows
// Q,K stored [bh][S][E] bf16 (Q pre-scaled), V stored transposed [bh][E][S].
// ---------------------------------------------------------------------------
__global__ __launch_bounds__(256) void qkv_kernel(
    const float* __restrict__ x, const float* __restrict__ wq,
    const float* __restrict__ wk, const float* __restrict__ wv,
    __bf16* __restrict__ Qb, __bf16* __restrict__ Kb, __bf16* __restrict__ VTb)
{
    __shared__ __align__(16) unsigned short wT[32][40];  // [e][d'] transposed, padded

    const int ho = blockIdx.x;
    const int rt = blockIdx.y;
    const int op = ho >> 3, h = ho & 7;
    const float* w = (op == 0) ? wq : (op == 1) ? wk : wv;

    const int tid = threadIdx.x;
    const int wid = tid >> 6, lane = tid & 63;
    const int c = lane & 15, g = lane >> 4;
    const int r0 = rt * 64;
    const int rowA = r0 + wid * 16 + c;

    f32x4 acc0 = {0.f, 0.f, 0.f, 0.f}, acc1 = {0.f, 0.f, 0.f, 0.f};

    for (int dt = 0; dt < D_; dt += 32) {
        // stage weight tile transposed into LDS (bf16)
        #pragma unroll
        for (int it = 0; it < 4; ++it) {
            int idx = it * 256 + tid;
            int i = idx >> 5, e = idx & 31;
            wT[e][i] = bfbits(w[(h * D_ + dt + i) * E_ + e]);
        }
        __syncthreads();

        // A fragment: x row, 8 fp32 -> bf16
        const float4* px = reinterpret_cast<const float4*>(x + rowA * D_ + dt + 8 * g);
        float4 f0 = px[0], f1 = px[1];
        bf16x8 a;
        a[0] = (__bf16)f0.x; a[1] = (__bf16)f0.y; a[2] = (__bf16)f0.z; a[3] = (__bf16)f0.w;
        a[4] = (__bf16)f1.x; a[5] = (__bf16)f1.y; a[6] = (__bf16)f1.z; a[7] = (__bf16)f1.w;

        bf16x8 b0 = *reinterpret_cast<const bf16x8*>(&wT[c][8 * g]);
        bf16x8 b1 = *reinterpret_cast<const bf16x8*>(&wT[16 + c][8 * g]);
        acc0 = __builtin_amdgcn_mfma_f32_16x16x32_bf16(a, b0, acc0, 0, 0, 0);
        acc1 = __builtin_amdgcn_mfma_f32_16x16x32_bf16(a, b1, acc1, 0, 0, 0);
        __syncthreads();
    }

    const float scale = (op == 0) ? QSCALE : 1.0f;
    #pragma unroll
    for (int i = 0; i < 4; ++i) {
        int row = r0 + wid * 16 + 4 * g + i;   // D-layout: row = 4g+i, col = c
        int b = row >> 11, s = row & 2047;
        int bh = b * 8 + h;
        float v0 = acc0[i] * scale, v1 = acc1[i] * scale;
        if (op < 2) {
            __bf16* dst = op ? Kb : Qb;
            dst[(bh * S_ + s) * E_ + c]      = (__bf16)v0;
            dst[(bh * S_ + s) * E_ + 16 + c] = (__bf16)v1;
        } else {
            VTb[(bh * E_ + c) * S_ + s]      = (__bf16)v0;
            VTb[(bh * E_ + 16 + c) * S_ + s] = (__bf16)v1;
        }
    }
}

// ---------------------------------------------------------------------------
// Kernel B: flash attention.  grid (32 qtiles, 32 bh), block 256 (4 waves).
// Each wave owns 16 q-rows. Swapped QK^T: S^T[k,q] = mfma(K, Q) so softmax
// state is per-lane (q = lane&15). ctx^T[e,q] accumulated via mfma(V^T, P^T).
// ---------------------------------------------------------------------------
__global__ __launch_bounds__(256) void attn_kernel(
    const __bf16* __restrict__ Qb, const __bf16* __restrict__ Kb,
    const __bf16* __restrict__ VTb, __bf16* __restrict__ CTX)
{
    __shared__ __align__(16) unsigned short pls[4][16][40];  // per-wave P tile [q][k]

    const int qt = blockIdx.x;
    const int bh = blockIdx.y;
    const int tid = threadIdx.x;
    const int wid = tid >> 6, lane = tid & 63;
    const int c = lane & 15, g = lane >> 4;
    const int q0 = qt * 64 + wid * 16;

    const __bf16* Qh = Qb + bh * S_ * E_;
    const __bf16* Kh = Kb + bh * S_ * E_;
    const __bf16* Vh = VTb + bh * E_ * S_;

    // Q fragment (B-operand of swapped mfma): Q[q=c][e=8g..8g+7], loaded once
    const bf16x8 qb = *reinterpret_cast<const bf16x8*>(Qh + (q0 + c) * E_ + 8 * g);

    f32x4 ctx0 = {0.f, 0.f, 0.f, 0.f}, ctx1 = {0.f, 0.f, 0.f, 0.f};
    const f32x4 zero = {0.f, 0.f, 0.f, 0.f};
    float m = -1e30f, lsum = 0.f;

    for (int kt = 0; kt < S_; kt += 32) {
        // K fragments (A-operand): rows kt+c and kt+16+c
        bf16x8 ka0 = *reinterpret_cast<const bf16x8*>(Kh + (kt + c) * E_ + 8 * g);
        bf16x8 ka1 = *reinterpret_cast<const bf16x8*>(Kh + (kt + 16 + c) * E_ + 8 * g);
        // V^T fragments for PV (A-operand): rows e=c and e=16+c, issued early
        bf16x8 va0 = *reinterpret_cast<const bf16x8*>(Vh + c * S_ + kt + 8 * g);
        bf16x8 va1 = *reinterpret_cast<const bf16x8*>(Vh + (16 + c) * S_ + kt + 8 * g);

        // S^T tiles: reg i of s1 -> k = kt + 4g + i; s2 -> k = kt + 16 + 4g + i; col q=c
        f32x4 s1 = __builtin_amdgcn_mfma_f32_16x16x32_bf16(ka0, qb, zero, 0, 0, 0);
        f32x4 s2 = __builtin_amdgcn_mfma_f32_16x16x32_bf16(ka1, qb, zero, 0, 0, 0);

        // online softmax (scores already in log2 units)
        float tmax = fmaxf(fmaxf(fmaxf(s1[0], s1[1]), fmaxf(s1[2], s1[3])),
                           fmaxf(fmaxf(s2[0], s2[1]), fmaxf(s2[2], s2[3])));
        tmax = fmaxf(tmax, __shfl_xor(tmax, 16, 64));
        tmax = fmaxf(tmax, __shfl_xor(tmax, 32, 64));
        float mnew = fmaxf(m, tmax);
        float factor = exp2f(m - mnew);
        float p1[4], p2[4];
        float psum = 0.f;
        #pragma unroll
        for (int i = 0; i < 4; ++i) {
            p1[i] = exp2f(s1[i] - mnew);
            p2[i] = exp2f(s2[i] - mnew);
            psum += p1[i] + p2[i];
        }
        psum += __shfl_xor(psum, 16, 64);
        psum += __shfl_xor(psum, 32, 64);
        lsum = lsum * factor + psum;
        m = mnew;
        #pragma unroll
        for (int i = 0; i < 4; ++i) { ctx0[i] *= factor; ctx1[i] *= factor; }

        // P -> bf16, LDS round-trip to PV B-fragment layout [q][k]
        *reinterpret_cast<uint2*>(&pls[wid][c][4 * g])      = make_uint2(pack2(p1[0], p1[1]), pack2(p1[2], p1[3]));
        *reinterpret_cast<uint2*>(&pls[wid][c][16 + 4 * g]) = make_uint2(pack2(p2[0], p2[1]), pack2(p2[2], p2[3]));
        __threadfence_block();  // order cross-lane LDS store -> load
        bf16x8 pb = *reinterpret_cast<const bf16x8*>(&pls[wid][c][8 * g]);

        ctx0 = __builtin_amdgcn_mfma_f32_16x16x32_bf16(va0, pb, ctx0, 0, 0, 0);
        ctx1 = __builtin_amdgcn_mfma_f32_16x16x32_bf16(va1, pb, ctx1, 0, 0, 0);
    }

    const float rinv = 1.0f / lsum;
    const int b = bh >> 3, h = bh & 7;
    const int s = q0 + c;
    #pragma unroll
    for (int i = 0; i < 4; ++i) {
        int e0 = 4 * g + i, e1 = 16 + 4 * g + i;   // ctx^T D-layout: row=e, col=q
        CTX[((b * S_ + s) * H_ + h) * E_ + e0] = (__bf16)(ctx0[i] * rinv);
        CTX[((b * S_ + s) * H_ + h) * E_ + e1] = (__bf16)(ctx1[i] * rinv);
    }
}

// ---------------------------------------------------------------------------
// Kernel C: output projection out = ctx @ wo.  grid (4, 128), block 256.
// ---------------------------------------------------------------------------
__global__ __launch_bounds__(256) void outproj_kernel(
    const __bf16* __restrict__ CTX, const float* __restrict__ wo,
    float* __restrict__ out)
{
    __shared__ __align__(16) unsigned short woT[64][40];  // [n'][d'] transposed

    const int nt = blockIdx.x;
    const int rt = blockIdx.y;
    const int tid = threadIdx.x;
    const int wid = tid >> 6, lane = tid & 63;
    const int c = lane & 15, g = lane >> 4;
    const int r0 = rt * 64;
    const int rowA = r0 + wid * 16 + c;

    f32x4 acc[4];
    #pragma unroll
    for (int f = 0; f < 4; ++f) acc[f] = (f32x4){0.f, 0.f, 0.f, 0.f};

    for (int dt = 0; dt < D_; dt += 32) {
        #pragma unroll
        for (int it = 0; it < 8; ++it) {
            int idx = it * 256 + tid;
            int i = idx >> 6, n = idx & 63;
            woT[n][i] = bfbits(wo[(dt + i) * D_ + nt * 64 + n]);
        }
        __syncthreads();

        bf16x8 a = *reinterpret_cast<const bf16x8*>(CTX + rowA * D_ + dt + 8 * g);
        #pragma unroll
        for (int f = 0; f < 4; ++f) {
            bf16x8 b = *reinterpret_cast<const bf16x8*>(&woT[16 * f + c][8 * g]);
            acc[f] = __builtin_amdgcn_mfma_f32_16x16x32_bf16(a, b, acc[f], 0, 0, 0);
        }
        __syncthreads();
    }

    #pragma unroll
    for (int f = 0; f < 4; ++f) {
        #pragma unroll
        for (int i = 0; i < 4; ++i) {
            int row = r0 + wid * 16 + 4 * g + i;
            out[row * D_ + nt * 64 + 16 * f + c] = acc[f][i];
        }
    }
}

// ---------------------------------------------------------------------------
extern "C" void kernel_launch(void* const* d_in, const int* in_sizes, int n_in,
                              void* d_out, int out_size, void* d_ws, size_t ws_size,
                              hipStream_t stream)
{
    (void)in_sizes; (void)n_in; (void)out_size; (void)ws_size;
    const float* x  = (const float*)d_in[0];
    const float* wq = (const float*)d_in[1];
    const float* wk = (const float*)d_in[2];
    const float* wv = (const float*)d_in[3];
    const float* wo = (const float*)d_in[4];
    float* out = (float*)d_out;

    char* ws = (char*)d_ws;
    __bf16* Qb  = (__bf16*)(ws);                     // 4 MB  [bh][S][E]
    __bf16* Kb  = (__bf16*)(ws + (4u << 20));        // 4 MB  [bh][S][E]
    __bf16* VTb = (__bf16*)(ws + (8u << 20));        // 4 MB  [bh][E][S]
    __bf16* CTX = (__bf16*)(ws + (12u << 20));       // 4 MB  [b][s][h][e]

    qkv_kernel<<<dim3(24, 128), 256, 0, stream>>>(x, wq, wk, wv, Qb, Kb, VTb);
    attn_kernel<<<dim3(32, 32), 256, 0, stream>>>(Qb, Kb, VTb, CTX);
    outproj_kernel<<<dim3(4, 128), 256, 0, stream>>>(CTX, wo, out);
}

// Round 2
// 87.807 us; speedup vs baseline: 1.7419x; 1.7419x over previous
//
#include <hip/hip_runtime.h>
#include <hip/hip_bf16.h>
#include <cstdint>

typedef __bf16 bf16x8 __attribute__((ext_vector_type(8)));
typedef float  f32x16 __attribute__((ext_vector_type(16)));
typedef unsigned int uint2v __attribute__((ext_vector_type(2)));

#define B_ 4
#define S_ 2048
#define D_ 256
#define H_ 8
#define E_ 32

// d_model^-0.5 * log2(e) folded into Q so softmax uses exp2 directly
#define QSCALE (0.0625f * 1.44269504088896f)

__device__ inline unsigned short bfbits(float f) {
    return __builtin_bit_cast(unsigned short, (__bf16)f);
}
__device__ inline unsigned int pack2(float a, float b) {
    return (unsigned int)bfbits(a) | ((unsigned int)bfbits(b) << 16);
}

// ---------------------------------------------------------------------------
// Prep: wT[(op*8+h)*32+e][d] = w_op[h][d][e] (bf16, Q pre-scaled). 196608 elems.
// ---------------------------------------------------------------------------
__global__ __launch_bounds__(256) void prep_kernel(
    const float* __restrict__ wq, const float* __restrict__ wk,
    const float* __restrict__ wv, __bf16* __restrict__ wT)
{
    int idx = blockIdx.x * 256 + threadIdx.x;      // < 3*8*256*32 = 196608
    int op = idx >> 16;
    int h  = (idx >> 13) & 7;
    int d  = (idx >> 5) & 255;
    int e  = idx & 31;
    const float* w = (op == 0) ? wq : (op == 1) ? wk : wv;
    float v = w[(h * D_ + d) * E_ + e];
    if (op == 0) v *= QSCALE;
    wT[(((op * H_ + h) * E_ + e) << 8) | d] = (__bf16)v;
}

// ---------------------------------------------------------------------------
// QKV: x(8192x256 f32) @ wT^T -> Q,K [bh][S][E], V^T [bh][E][S]  (bf16)
// grid 256 blocks (32 rows each), 4 waves; wave holds its A-row frags in regs
// and iterates 6 of the 24 col-tiles. B-frags are direct b128 loads (L2).
// ---------------------------------------------------------------------------
__global__ __launch_bounds__(256, 2) void qkv_kernel(
    const float* __restrict__ x, const __bf16* __restrict__ wT,
    __bf16* __restrict__ Qb, __bf16* __restrict__ Kb, __bf16* __restrict__ VTb)
{
    const int tid = threadIdx.x;
    const int wid = tid >> 6, lane = tid & 63;
    const int c = lane & 31, hi = lane >> 5;
    const int row0 = blockIdx.x * 32;
    const int row = row0 + c;

    // A-fragments: step t covers d = 16t + 8*hi + (0..7)
    bf16x8 a[16];
    #pragma unroll
    for (int t = 0; t < 16; ++t) {
        const float4* px = reinterpret_cast<const float4*>(x + row * D_ + 16 * t + 8 * hi);
        float4 f0 = px[0], f1 = px[1];
        bf16x8 v;
        v[0]=(__bf16)f0.x; v[1]=(__bf16)f0.y; v[2]=(__bf16)f0.z; v[3]=(__bf16)f0.w;
        v[4]=(__bf16)f1.x; v[5]=(__bf16)f1.y; v[6]=(__bf16)f1.z; v[7]=(__bf16)f1.w;
        a[t] = v;
    }

    const int b  = row0 >> 11;
    const int s0 = row0 & (S_ - 1);

    for (int j = 0; j < 6; ++j) {
        const int ct = wid * 6 + j;                // 0..23
        const int op = ct >> 3, h = ct & 7;
        const int col = ct * 32 + c;
        const __bf16* wp = wT + col * 256 + 8 * hi;

        f32x16 acc = {};
        #pragma unroll
        for (int t = 0; t < 16; ++t) {
            bf16x8 bb = *reinterpret_cast<const bf16x8*>(wp + 16 * t);
            acc = __builtin_amdgcn_mfma_f32_32x32x16_bf16(a[t], bb, acc, 0, 0, 0);
        }

        const int bh = b * H_ + h;
        if (op < 2) {
            __bf16* dst = (op == 0 ? Qb : Kb) + (size_t)bh * S_ * E_ + c;
            #pragma unroll
            for (int r = 0; r < 16; ++r) {
                int rr = (r & 3) + 8 * (r >> 2) + 4 * hi;
                dst[(size_t)(s0 + rr) * E_] = (__bf16)acc[r];
            }
        } else {
            __bf16* dst = VTb + ((size_t)bh * E_ + c) * S_ + s0;
            #pragma unroll
            for (int g4 = 0; g4 < 4; ++g4) {
                unsigned int lo  = pack2(acc[4*g4],   acc[4*g4+1]);
                unsigned int hi2 = pack2(acc[4*g4+2], acc[4*g4+3]);
                *reinterpret_cast<uint2*>(dst + 8 * g4 + 4 * hi) = make_uint2(lo, hi2);
            }
        }
    }
}

// ---------------------------------------------------------------------------
// Flash attention, 32x32 swapped form, no LDS, no syncthreads.
// grid (16, 32), block 256 = 4 independent waves, each owns 32 q-rows.
// S^T[k][q] = mfma(K, Q); lane holds 16 scores of one q (col = lane&31).
// P^T B-frag built in-register via pack + permlane32_swap.
// ctx^T[e][q] = mfma(V^T, P^T).  Defer-max with THR=8 (log2 units).
// ---------------------------------------------------------------------------
__global__ __launch_bounds__(256, 2) void attn_kernel(
    const __bf16* __restrict__ Qb, const __bf16* __restrict__ Kb,
    const __bf16* __restrict__ VTb, __bf16* __restrict__ CTX)
{
    const int tid = threadIdx.x;
    const int wid = tid >> 6, lane = tid & 63;
    const int c = lane & 31, hi = lane >> 5;
    const int bh = blockIdx.y;
    const int q0 = (blockIdx.x * 4 + wid) * 32;
    const bool islo = (hi == 0);

    const __bf16* Qh    = Qb + (size_t)bh * S_ * E_;
    const __bf16* kbase = Kb + (size_t)bh * S_ * E_ + c * E_ + 8 * hi;
    const __bf16* vbase = VTb + (size_t)bh * E_ * S_ + c * S_ + 8 * hi;

    const bf16x8 qb0 = *reinterpret_cast<const bf16x8*>(Qh + (q0 + c) * E_ + 8 * hi);
    const bf16x8 qb1 = *reinterpret_cast<const bf16x8*>(Qh + (q0 + c) * E_ + 16 + 8 * hi);

    f32x16 ctx = {};
    float m = -1e30f, lsum = 0.f;

    bf16x8 kA0, kA1, vA0, vA1, kB0, kB1, vB0, vB1;

#define LOADSET(K0, K1, V0, V1, kt) do { \
    K0 = *reinterpret_cast<const bf16x8*>(kbase + (size_t)(kt) * E_);      \
    K1 = *reinterpret_cast<const bf16x8*>(kbase + (size_t)(kt) * E_ + 16); \
    V0 = *reinterpret_cast<const bf16x8*>(vbase + (kt));                   \
    V1 = *reinterpret_cast<const bf16x8*>(vbase + (kt) + 16); } while (0)

    auto xpartner = [&](float v) -> float {
        uint2v r = __builtin_amdgcn_permlane32_swap(
            __builtin_bit_cast(unsigned int, v),
            __builtin_bit_cast(unsigned int, v), false, false);
        return __builtin_bit_cast(float, islo ? r[1] : r[0]);
    };

    auto compute = [&](const bf16x8& K0, const bf16x8& K1,
                       const bf16x8& V0, const bf16x8& V1) {
        f32x16 sc = {};
        sc = __builtin_amdgcn_mfma_f32_32x32x16_bf16(K0, qb0, sc, 0, 0, 0);
        sc = __builtin_amdgcn_mfma_f32_32x32x16_bf16(K1, qb1, sc, 0, 0, 0);

        float t = sc[0];
        #pragma unroll
        for (int i = 1; i < 16; ++i) t = fmaxf(t, sc[i]);
        t = fmaxf(t, xpartner(t));

        if (!__all(t <= m + 8.0f)) {          // rescale (rare after tile 0)
            float mnew = fmaxf(m, t);
            float f = __builtin_amdgcn_exp2f(m - mnew);
            lsum *= f;
            #pragma unroll
            for (int i = 0; i < 16; ++i) ctx[i] *= f;
            m = mnew;
        }

        float p[16], psum = 0.f;
        #pragma unroll
        for (int i = 0; i < 16; ++i) {
            p[i] = __builtin_amdgcn_exp2f(sc[i] - m);
            psum += p[i];
        }
        psum += xpartner(psum);
        lsum += psum;

        // PV B-frag, k-half 0 (k 0..15): regs p0..p7
        unsigned int c0 = pack2(p[0], p[1]), c1 = pack2(p[2], p[3]);
        unsigned int c2 = pack2(p[4], p[5]), c3 = pack2(p[6], p[7]);
        uint2v r02 = __builtin_amdgcn_permlane32_swap(c0, c2, false, false);
        uint2v r13 = __builtin_amdgcn_permlane32_swap(c1, c3, false, false);
        uint4 u0; u0.x = r02[0]; u0.y = r13[0]; u0.z = r02[1]; u0.w = r13[1];
        // k-half 1 (k 16..31): regs p8..p15
        c0 = pack2(p[8], p[9]);   c1 = pack2(p[10], p[11]);
        c2 = pack2(p[12], p[13]); c3 = pack2(p[14], p[15]);
        r02 = __builtin_amdgcn_permlane32_swap(c0, c2, false, false);
        r13 = __builtin_amdgcn_permlane32_swap(c1, c3, false, false);
        uint4 u1; u1.x = r02[0]; u1.y = r13[0]; u1.z = r02[1]; u1.w = r13[1];

        __builtin_amdgcn_s_setprio(1);
        ctx = __builtin_amdgcn_mfma_f32_32x32x16_bf16(V0, __builtin_bit_cast(bf16x8, u0), ctx, 0, 0, 0);
        ctx = __builtin_amdgcn_mfma_f32_32x32x16_bf16(V1, __builtin_bit_cast(bf16x8, u1), ctx, 0, 0, 0);
        __builtin_amdgcn_s_setprio(0);
    };

    LOADSET(kA0, kA1, vA0, vA1, 0);
    for (int kt = 0; kt < S_; kt += 64) {
        LOADSET(kB0, kB1, vB0, vB1, kt + 32);
        compute(kA0, kA1, vA0, vA1);
        int ktn = (kt + 64) & (S_ - 1);        // wrap keeps prefetch in-bounds
        LOADSET(kA0, kA1, vA0, vA1, ktn);
        compute(kB0, kB1, vB0, vB1);
    }

    const float rinv = 1.0f / lsum;
    const int b = bh >> 3, h = bh & 7;
    __bf16* dst = CTX + (((size_t)b * S_ + (q0 + c)) * H_ + h) * E_ + 4 * hi;
    #pragma unroll
    for (int g4 = 0; g4 < 4; ++g4) {
        unsigned int lo  = pack2(ctx[4*g4]   * rinv, ctx[4*g4+1] * rinv);
        unsigned int hi2 = pack2(ctx[4*g4+2] * rinv, ctx[4*g4+3] * rinv);
        *reinterpret_cast<uint2*>(dst + 8 * g4) = make_uint2(lo, hi2);
    }
#undef LOADSET
}

// ---------------------------------------------------------------------------
// Outproj: out(8192x256 f32) = CTX(bf16) @ wo(f32).  grid 256, 4 waves,
// wave = 32 rows x 2 col-tiles; wo gathered+converted on the fly.
// ---------------------------------------------------------------------------
__global__ __launch_bounds__(256, 2) void outproj_kernel(
    const __bf16* __restrict__ CTX, const float* __restrict__ wo,
    float* __restrict__ out)
{
    const int tid = threadIdx.x;
    const int wid = tid >> 6, lane = tid & 63;
    const int c = lane & 31, hi = lane >> 5;
    const int row0 = blockIdx.x * 32;
    const int row = row0 + c;

    bf16x8 a[16];
    #pragma unroll
    for (int t = 0; t < 16; ++t)
        a[t] = *reinterpret_cast<const bf16x8*>(CTX + row * D_ + 16 * t + 8 * hi);

    for (int j = 0; j < 2; ++j) {
        const int ct = wid * 2 + j;               // 0..7
        const int col = ct * 32 + c;
        f32x16 acc = {};
        #pragma unroll
        for (int t = 0; t < 16; ++t) {
            const float* wp = wo + (16 * t + 8 * hi) * D_ + col;
            bf16x8 bb;
            #pragma unroll
            for (int i = 0; i < 8; ++i) bb[i] = (__bf16)wp[i * D_];
            acc = __builtin_amdgcn_mfma_f32_32x32x16_bf16(a[t], bb, acc, 0, 0, 0);
        }
        float* op = out + (size_t)row0 * D_ + ct * 32 + c;
        #pragma unroll
        for (int r = 0; r < 16; ++r) {
            int rr = (r & 3) + 8 * (r >> 2) + 4 * hi;
            op[rr * D_] = acc[r];
        }
    }
}

// ---------------------------------------------------------------------------
extern "C" void kernel_launch(void* const* d_in, const int* in_sizes, int n_in,
                              void* d_out, int out_size, void* d_ws, size_t ws_size,
                              hipStream_t stream)
{
    (void)in_sizes; (void)n_in; (void)out_size; (void)ws_size;
    const float* x  = (const float*)d_in[0];
    const float* wq = (const float*)d_in[1];
    const float* wk = (const float*)d_in[2];
    const float* wv = (const float*)d_in[3];
    const float* wo = (const float*)d_in[4];
    float* out = (float*)d_out;

    char* ws = (char*)d_ws;
    __bf16* Qb  = (__bf16*)(ws);                  // 4 MB  [bh][S][E]
    __bf16* Kb  = (__bf16*)(ws + (4u  << 20));    // 4 MB  [bh][S][E]
    __bf16* VTb = (__bf16*)(ws + (8u  << 20));    // 4 MB  [bh][E][S]
    __bf16* CTX = (__bf16*)(ws + (12u << 20));    // 4 MB  [b][s][h][e]
    __bf16* wT  = (__bf16*)(ws + (12u << 20));    // 384 KB, dead before CTX written

    prep_kernel<<<768, 256, 0, stream>>>(wq, wk, wv, wT);
    qkv_kernel<<<256, 256, 0, stream>>>(x, wT, Qb, Kb, VTb);
    attn_kernel<<<dim3(16, 32), 256, 0, stream>>>(Qb, Kb, VTb, CTX);
    outproj_kernel<<<256, 256, 0, stream>>>(CTX, wo, out);
}